// Round 1
// baseline (11404.996 us; speedup 1.0000x reference)
//
#include <hip/hip_runtime.h>

// Problem constants
#define B_   32
#define T_   256
#define N_   128
#define DIN_ 16
#define U_   64

// LDS layout (ushort elements)
#define PD 392   // node-major diffusion buffer pitch (>=384, +8 for bank stagger)
#define PT 136   // ch-major (transposed) buffer pitch (>=128, +8 stagger)
#define LDS_US  (N_*PD + N_*PT)
#define LDS_BYTES (LDS_US*2)     // 135168 B

// Pre-transposed weight workspace layout (ushort elems): WT[co][k], k = dm*Cin + c
#define WT0G_OFF 0
#define WT0C_OFF (128*256)
#define WT1G_OFF (WT0C_OFF + 64*256)
#define WT1C_OFF (WT1G_OFF + 128*384)
#define WT_TOTAL (WT1C_OFF + 64*384)   // 122880 ushorts = 245760 B

typedef __attribute__((ext_vector_type(8))) short bfrag;          // 8 bf16 (4 VGPR)
typedef __attribute__((ext_vector_type(4))) float ffrag;          // MFMA C/D
typedef __attribute__((ext_vector_type(4))) unsigned short us4;

__device__ __forceinline__ unsigned short f2b(float x) {          // fp32 -> bf16 RNE
  union { float f; unsigned u; } v; v.f = x;
  return (unsigned short)((v.u + 0x7fffu + ((v.u >> 16) & 1u)) >> 16);
}
__device__ __forceinline__ float sigm(float x) {
  float e = __expf(-x);
#if __has_builtin(__builtin_amdgcn_rcpf)
  return __builtin_amdgcn_rcpf(1.f + e);
#else
  return 1.f / (1.f + e);
#endif
}
__device__ __forceinline__ float tanh_(float x) {
  float e = __expf(2.f * x);   // tanh = 1 - 2/(1+e^{2x}); saturates cleanly, no NaN
#if __has_builtin(__builtin_amdgcn_rcpf)
  return 1.f - 2.f * __builtin_amdgcn_rcpf(1.f + e);
#else
  return 1.f - 2.f / (1.f + e);
#endif
}

// Chebyshev fold: dm0 -> W0 - W2, dm1 -> W1, dm2 -> 2*W2  (x2 = 2*S*x1 - x0 absorbed)
__device__ __forceinline__ float wval(const float* w, int ncol, int cin, int K,
                                      int co, int k) {
  if (k >= K) return 0.f;                 // zero K-pad (L0: 240 -> 256)
  int dm = k / cin, c = k - dm * cin;     // our k-order: matrix-major
  if (dm == 0) return w[(c*3 + 0)*ncol + co] - w[(c*3 + 2)*ncol + co];
  if (dm == 1) return w[(c*3 + 1)*ncol + co];
  return 2.f * w[(c*3 + 2)*ncol + co];
}

__global__ void setup_wt(const float* __restrict__ w0g, const float* __restrict__ w0c,
                         const float* __restrict__ w1g, const float* __restrict__ w1c,
                         unsigned short* __restrict__ wt) {
  int i = blockIdx.x * blockDim.x + threadIdx.x;
  if (i >= WT_TOTAL) return;
  float v;
  if (i < WT0C_OFF) {
    int co = i >> 8, k = i & 255;
    v = wval(w0g, 128, 80, 240, co, k);
  } else if (i < WT1G_OFF) {
    int j = i - WT0C_OFF; int co = j >> 8, k = j & 255;
    v = wval(w0c, 64, 80, 240, co, k);
  } else if (i < WT1C_OFF) {
    int j = i - WT1G_OFF; int co = j / 384, k = j - co*384;
    v = wval(w1g, 128, 128, 384, co, k);
  } else {
    int j = i - WT1C_OFF; int co = j / 384, k = j - co*384;
    v = wval(w1c, 64, 128, 384, co, k);
  }
  wt[i] = f2b(v);
}

// Weight GEMM, node-split: wave w owns nodes [32w,32w+32), all NT co-tiles.
// A (activations) from LDS node-major diff; B (weights) streamed from global WT.
template<int KT, int NT>
__device__ __forceinline__ void wgemm(ffrag (&acc)[2][NT],
    const unsigned short* __restrict__ diffp,
    const unsigned short* __restrict__ wtp, const int Kpad,
    const int w, const int ln, const int lq) {
  const ffrag fz = {0.f, 0.f, 0.f, 0.f};
#pragma unroll
  for (int m = 0; m < 2; ++m)
#pragma unroll
    for (int n = 0; n < NT; ++n) acc[m][n] = fz;
  bfrag bw[NT], bn[NT];
#pragma unroll
  for (int n = 0; n < NT; ++n)
    bw[n] = *(const bfrag*)&wtp[(16*n + ln)*Kpad + 8*lq];
#pragma unroll
  for (int ks = 0; ks < KT; ++ks) {
    if (ks + 1 < KT) {
#pragma unroll
      for (int n = 0; n < NT; ++n)               // 1-deep global prefetch
        bn[n] = *(const bfrag*)&wtp[(16*n + ln)*Kpad + 32*(ks+1) + 8*lq];
    }
    bfrag a0 = *(const bfrag*)&diffp[(32*w      + ln)*PD + 32*ks + 8*lq];
    bfrag a1 = *(const bfrag*)&diffp[(32*w + 16 + ln)*PD + 32*ks + 8*lq];
#pragma unroll
    for (int n = 0; n < NT; ++n) {
      acc[0][n] = __builtin_amdgcn_mfma_f32_16x16x32_bf16(a0, bw[n], acc[0][n], 0,0,0);
      acc[1][n] = __builtin_amdgcn_mfma_f32_16x16x32_bf16(a1, bw[n], acc[1][n], 0,0,0);
    }
    if (ks + 1 < KT) {
#pragma unroll
      for (int n = 0; n < NT; ++n) bw[n] = bn[n];
    }
  }
}

__global__ __launch_bounds__(256, 1) void dcgru(
    const float* __restrict__ xseq, const int* __restrict__ slen,
    const float* __restrict__ sup,
    const float* __restrict__ b0g, const float* __restrict__ b0c,
    const float* __restrict__ b1g, const float* __restrict__ b1c,
    const float* __restrict__ wfc, const float* __restrict__ bfc,
    const unsigned short* __restrict__ wt, float* __restrict__ out) {
  extern __shared__ unsigned short lds[];
  unsigned short* diffb = lds;             // [128][PD] node-major, k = dm*Cin+c
  unsigned short* difT  = lds + N_*PD;     // [128][PT] ch-major (S-GEMM B operand)
  const int b   = blockIdx.x;
  const int tid = threadIdx.x;
  const int w   = tid >> 6;                // wave 0..3
  const int ln  = tid & 15;                // lane&15
  const int lq  = (tid >> 4) & 3;          // quad
  const int L   = slen[b];

  // ---- S resident in registers as MFMA A-fragments (reused 8 GEMMs/step) ----
  bfrag Sf[8][4];
#pragma unroll
  for (int mt = 0; mt < 8; ++mt)
#pragma unroll
    for (int ks = 0; ks < 4; ++ks) {
      const float* p = sup + (16*mt + ln)*N_ + 32*ks + 8*lq;
      union { bfrag v; unsigned short u[8]; } tmp;
#pragma unroll
      for (int j = 0; j < 8; ++j) tmp.u[j] = f2b(p[j]);
      Sf[mt][ks] = tmp.v;
    }

  float bgv0[8], bcv0[4], bgv1[8], bcv1[4];
#pragma unroll
  for (int n = 0; n < 8; ++n) bgv0[n] = b0g[16*n + ln];
#pragma unroll
  for (int n = 0; n < 4; ++n) bcv0[n] = b0c[16*n + ln];
#pragma unroll
  for (int n = 0; n < 8; ++n) bgv1[n] = b1g[16*n + ln];
#pragma unroll
  for (int n = 0; n < 4; ++n) bcv1[n] = b1c[16*n + ln];

  // fp32 master hidden states in registers; wave w owns nodes [32w,32w+32) x all ch.
  // layout mirrors MFMA C/D frag: value[node=32w+16*m2+4*lq+r][ch=16*ct+ln]
  ffrag h0m[2][4], h1m[2][4];
  const ffrag fz = {0.f, 0.f, 0.f, 0.f};
#pragma unroll
  for (int m = 0; m < 2; ++m)
#pragma unroll
    for (int c = 0; c < 4; ++c) { h0m[m][c] = fz; h1m[m][c] = fz; }

  // zero L0 K-pad cols [240,256) once (weights there are 0; just avoid NaN garbage)
  for (int i = tid; i < N_*16; i += 256)
    diffb[(i >> 4)*PD + 240 + (i & 15)] = 0;

  // Diffusion GEMM D = S @ X, channel-split: this wave computes ch-tile nt (all 128
  // nodes). B-frags from difT rows of tile nt (wave-private: in-place update safe).
  auto diffuse = [&](int nt, int outbase, bool wT) {
    ffrag acc[8];
#pragma unroll
    for (int mt = 0; mt < 8; ++mt) acc[mt] = fz;
#pragma unroll
    for (int ks = 0; ks < 4; ++ks) {
      bfrag bf = *(const bfrag*)&difT[(16*nt + ln)*PT + 32*ks + 8*lq];
#pragma unroll
      for (int mt = 0; mt < 8; ++mt)
        acc[mt] = __builtin_amdgcn_mfma_f32_16x16x32_bf16(Sf[mt][ks], bf, acc[mt], 0,0,0);
    }
    const int ch = 16*nt + ln;
#pragma unroll
    for (int mt = 0; mt < 8; ++mt) {
      const int node0 = 16*mt + 4*lq;
      unsigned short sv[4];
#pragma unroll
      for (int r = 0; r < 4; ++r) sv[r] = f2b(acc[mt][r]);
#pragma unroll
      for (int r = 0; r < 4; ++r) diffb[(node0 + r)*PD + outbase + ch] = sv[r];
      if (wT) {
        us4 p4 = {sv[0], sv[1], sv[2], sv[3]};
        *(us4*)&difT[ch*PT + node0] = p4;      // 4 consecutive nodes -> b64
      }
    }
  };

  // Dump an h-like reg tile (this wave's node strip, all 64 ch) into both layouts.
  auto dumpH = [&](ffrag (&v)[2][4], int cb) {
#pragma unroll
    for (int m2 = 0; m2 < 2; ++m2)
#pragma unroll
      for (int ct = 0; ct < 4; ++ct) {
        const int ch = cb + 16*ct + ln;
        const int node0 = 32*w + 16*m2 + 4*lq;
        unsigned short sv[4];
#pragma unroll
        for (int r = 0; r < 4; ++r) sv[r] = f2b(v[m2][ct][r]);
#pragma unroll
        for (int r = 0; r < 4; ++r) diffb[(node0 + r)*PD + ch] = sv[r];
        us4 p4 = {sv[0], sv[1], sv[2], sv[3]};
        *(us4*)&difT[ch*PT + node0] = p4;
      }
  };

#pragma clang loop unroll(disable)
  for (int t = 0; t < L; ++t) {
    ffrag u0s[2][4], u1s[2][4];
    // ---------------- Layer 0 (Cin=80: x cols 0..15, h cols 16..79) -------------
    {  // phase a: stage x_t (own node strip) + h0 into dm0 cols of both buffers
      const float* xp = xseq + ((b*T_ + t)*N_*DIN_) + w*512;
#pragma unroll
      for (int i = 0; i < 8; ++i) {
        int f = (tid & 63) + 64*i;
        int node = 32*w + (f >> 4), c = f & 15;
        unsigned short v = f2b(xp[f]);
        diffb[node*PD + c] = v;
        difT[c*PT + node] = v;
      }
    }
    dumpH(h0m, DIN_);
    __syncthreads();                                   // B1
    diffuse(w, 80, true);                              // x1 = S@[x|h]  (tiles 0..4)
    if (w == 0) diffuse(4, 80, true);
    diffuse(w, 160, false);                            // y = S@x1 (weights folded)
    if (w == 0) diffuse(4, 160, false);
    __syncthreads();                                   // B2
    {
      ffrag ga[2][8];
      wgemm<8, 8>(ga, diffb, wt + WT0G_OFF, 256, w, ln, lq);
      ffrag rh[2][4];
#pragma unroll
      for (int m2 = 0; m2 < 2; ++m2)
#pragma unroll
        for (int n = 0; n < 8; ++n)
#pragma unroll
          for (int r = 0; r < 4; ++r) {
            float s = sigm(ga[m2][n][r] + bgv0[n]);
            if (n < 4) rh[m2][n][r] = s * h0m[m2][n][r];   // r*h
            else       u0s[m2][n-4][r] = s;                // u
          }
      dumpH(rh, DIN_);                                 // overwrite h-cols with r*h
    }
    __syncthreads();                                   // B3
    diffuse(1 + w, 80, true);                          // S@(r*h)   (tiles 1..4)
    diffuse(1 + w, 160, false);                        // S@S@(r*h)
    __syncthreads();                                   // B4
    {
      ffrag ca[2][4];
      wgemm<8, 4>(ca, diffb, wt + WT0C_OFF, 256, w, ln, lq);
#pragma unroll
      for (int m2 = 0; m2 < 2; ++m2)
#pragma unroll
        for (int n = 0; n < 4; ++n)
#pragma unroll
          for (int r = 0; r < 4; ++r) {
            float cc = tanh_(ca[m2][n][r] + bcv0[n]);
            float uu = u0s[m2][n][r];
            h0m[m2][n][r] = uu*h0m[m2][n][r] + (1.f - uu)*cc;  // h0 <- new
          }
    }
    // ---------------- Layer 1 (Cin=128: x=h0' cols 0..63, h cols 64..127) ------
    dumpH(h0m, 0);
    dumpH(h1m, 64);
    __syncthreads();                                   // B5
    diffuse(w, 128, true);  diffuse(4 + w, 128, true);   // S@[h0'|h1]
    diffuse(w, 256, false); diffuse(4 + w, 256, false);  // S@x1
    __syncthreads();                                   // B6
    {
      ffrag ga[2][8];
      wgemm<12, 8>(ga, diffb, wt + WT1G_OFF, 384, w, ln, lq);
      ffrag rh[2][4];
#pragma unroll
      for (int m2 = 0; m2 < 2; ++m2)
#pragma unroll
        for (int n = 0; n < 8; ++n)
#pragma unroll
          for (int r = 0; r < 4; ++r) {
            float s = sigm(ga[m2][n][r] + bgv1[n]);
            if (n < 4) rh[m2][n][r] = s * h1m[m2][n][r];
            else       u1s[m2][n-4][r] = s;
          }
      dumpH(rh, 64);
    }
    __syncthreads();                                   // B7
    diffuse(4 + w, 128, true);                         // S@(r*h1)  (tiles 4..7)
    diffuse(4 + w, 256, false);                        // S@S@(r*h1)
    __syncthreads();                                   // B8
    {
      ffrag ca[2][4];
      wgemm<12, 4>(ca, diffb, wt + WT1C_OFF, 384, w, ln, lq);
#pragma unroll
      for (int m2 = 0; m2 < 2; ++m2)
#pragma unroll
        for (int n = 0; n < 4; ++n)
#pragma unroll
          for (int r = 0; r < 4; ++r) {
            float cc = tanh_(ca[m2][n][r] + bcv1[n]);
            float uu = u1s[m2][n][r];
            h1m[m2][n][r] = uu*h1m[m2][n][r] + (1.f - uu)*cc;
          }
    }
  }

  // ---------------- Head: relu(h1) @ W_fc + b_fc, max over nodes ----------------
  __syncthreads();
  {
    float* hb = (float*)lds;                 // [128][64] relu'd last hidden
#pragma unroll
    for (int m2 = 0; m2 < 2; ++m2)
#pragma unroll
      for (int ct = 0; ct < 4; ++ct)
#pragma unroll
        for (int r = 0; r < 4; ++r) {
          int node = 32*w + 16*m2 + 4*lq + r;
          int ch = 16*ct + ln;
          float v = h1m[m2][ct][r];
          hb[node*U_ + ch] = v > 0.f ? v : 0.f;
        }
  }
  __syncthreads();
  float* hb = (float*)lds;
  float* lb = hb + N_*U_;                    // [128][4] logits
  if (tid < N_) {
    float lg[4];
#pragma unroll
    for (int j = 0; j < 4; ++j) lg[j] = bfc[j];
    for (int ch = 0; ch < U_; ++ch) {
      float v = hb[tid*U_ + ch];
#pragma unroll
      for (int j = 0; j < 4; ++j) lg[j] += v * wfc[ch*4 + j];
    }
#pragma unroll
    for (int j = 0; j < 4; ++j) lb[tid*4 + j] = lg[j];
  }
  __syncthreads();
  if (tid < 4) {
    float m = lb[tid];
    for (int n = 1; n < N_; ++n) m = fmaxf(m, lb[n*4 + tid]);
    out[b*4 + tid] = m;
  }
}

extern "C" void kernel_launch(void* const* d_in, const int* in_sizes, int n_in,
                              void* d_out, int out_size, void* d_ws, size_t ws_size,
                              hipStream_t stream) {
  const float* xseq = (const float*)d_in[0];
  const int*   slen = (const int*)  d_in[1];
  const float* sup  = (const float*)d_in[2];
  const float* w0g  = (const float*)d_in[3];
  const float* b0g  = (const float*)d_in[4];
  const float* w0c  = (const float*)d_in[5];
  const float* b0c  = (const float*)d_in[6];
  const float* w1g  = (const float*)d_in[7];
  const float* b1g  = (const float*)d_in[8];
  const float* w1c  = (const float*)d_in[9];
  const float* b1c  = (const float*)d_in[10];
  const float* wfc  = (const float*)d_in[11];
  const float* bfc  = (const float*)d_in[12];
  float* out = (float*)d_out;
  unsigned short* wt = (unsigned short*)d_ws;

  (void)hipFuncSetAttribute((const void*)dcgru,
                            hipFuncAttributeMaxDynamicSharedMemorySize, LDS_BYTES);
  setup_wt<<<dim3((WT_TOTAL + 255)/256), dim3(256), 0, stream>>>(w0g, w0c, w1g, w1c, wt);
  dcgru<<<dim3(B_), dim3(256), LDS_BYTES, stream>>>(
      xseq, slen, sup, b0g, b0c, b1g, b1c, wfc, bfc, wt, out);
}